// Round 9
// baseline (363.512 us; speedup 1.0000x reference)
//
#include <hip/hip_runtime.h>
#include <math.h>

// Problem constants (B=2, T=2048, C=2048, HQ=16, HKV=4, Dh=128, WIN=256)
#define BB   2
#define TT   2048
#define CC   2048
#define HQ_  16
#define HKV_ 4
#define DH   128
#define MM   (BB * TT)          // 4096 rows
#define KVC  (HKV_ * DH)        // 512

typedef __attribute__((ext_vector_type(8)))  _Float16 f16x8;
typedef __attribute__((ext_vector_type(4)))  float    f32x4;
typedef __attribute__((ext_vector_type(16))) float    f32x16;

__device__ __forceinline__ unsigned short f2h(float x) {
    _Float16 h = (_Float16)x;                 // RNE v_cvt_f16_f32
    return __builtin_bit_cast(unsigned short, h);
}
__device__ __forceinline__ float h2f(unsigned short u) {
    return (float)__builtin_bit_cast(_Float16, u);
}
__device__ __forceinline__ void gll16(const void* g, void* l) {
    __builtin_amdgcn_global_load_lds(
        (const __attribute__((address_space(1))) unsigned int*)g,
        (__attribute__((address_space(3))) unsigned int*)l, 16, 0, 0);
}
// bijective XCD-aware tile remap (T1, m204 form). Assumes consecutive launch
// ids round-robin across 8 XCDs; gives each XCD a contiguous tile chunk.
__device__ __forceinline__ int xcd_swizzle(int lid, int nwg) {
    const int xcd = lid & 7, rank = lid >> 3;
    const int q8 = nwg >> 3, r8 = nwg & 7;
    return (xcd < r8 ? xcd * (q8 + 1) : r8 * (q8 + 1) + (xcd - r8) * q8) + rank;
}

// ---------------------------------------------------------------------------
// fp32 -> fp16 cast, 8 elems/thread
// ---------------------------------------------------------------------------
__global__ __launch_bounds__(256)
void cast_f16(const float* __restrict__ in, unsigned short* __restrict__ out, int n8) {
    int i = blockIdx.x * blockDim.x + threadIdx.x;
    const int stride = gridDim.x * blockDim.x;
    for (; i < n8; i += stride) {
        const float4 a = ((const float4*)in)[i * 2 + 0];
        const float4 b = ((const float4*)in)[i * 2 + 1];
        uint4 o;
        o.x = (unsigned)f2h(a.x) | ((unsigned)f2h(a.y) << 16);
        o.y = (unsigned)f2h(a.z) | ((unsigned)f2h(a.w) << 16);
        o.z = (unsigned)f2h(b.x) | ((unsigned)f2h(b.y) << 16);
        o.w = (unsigned)f2h(b.z) | ((unsigned)f2h(b.w) << 16);
        ((uint4*)out)[i] = o;
    }
}

// ---------------------------------------------------------------------------
// Transpose-cast: W[Kd][Nd] fp32 -> WT[Nd][Kd] fp16. 32x32 tiles.
// ---------------------------------------------------------------------------
__global__ __launch_bounds__(256)
void tcast(const float* __restrict__ W, unsigned short* __restrict__ WT, int Kd, int Nd) {
    __shared__ float Ls[32][33];
    const int n0 = blockIdx.x * 32, k0 = blockIdx.y * 32;
    const int i = threadIdx.x;
    {
        const int kr = i >> 3, n4 = (i & 7) * 4;
        float4 v = *(const float4*)&W[(size_t)(k0 + kr) * Nd + n0 + n4];
        Ls[kr][n4 + 0] = v.x; Ls[kr][n4 + 1] = v.y;
        Ls[kr][n4 + 2] = v.z; Ls[kr][n4 + 3] = v.w;
    }
    __syncthreads();
    {
        const int nr = i >> 3, k4 = (i & 7) * 4;
        uint2 o;
        o.x = (unsigned)f2h(Ls[k4 + 0][nr]) | ((unsigned)f2h(Ls[k4 + 1][nr]) << 16);
        o.y = (unsigned)f2h(Ls[k4 + 2][nr]) | ((unsigned)f2h(Ls[k4 + 3][nr]) << 16);
        *(uint2*)&WT[(size_t)(n0 + nr) * Kd + k0 + k4] = o;
    }
}

// ---------------------------------------------------------------------------
// fp16 MFMA GEMM, B^T input: C[M][N] = A[M][K] * Bt[N][K]^T
// 128x128 tile, BK=64, 4 waves, acc 4x4 frags/wave, global_load_lds staging,
// 3-bit XOR chunk-swizzle, + R9: XCD-aware tile swizzle (T1).
// ---------------------------------------------------------------------------
template<int F16OUT>
__global__ __launch_bounds__(256)
void gemm_bt(const unsigned short* __restrict__ A, const unsigned short* __restrict__ Bt,
             void* __restrict__ Cout, int M, int N, int K) {
    __shared__ __align__(16) unsigned short As[128 * 64];
    __shared__ __align__(16) unsigned short Bs[128 * 64];
    const int tid  = threadIdx.x;
    const int lane = tid & 63, wid = tid >> 6;
    const int g = lane >> 4, l15 = lane & 15;
    const int nwg  = gridDim.x * gridDim.y;
    const int tile = xcd_swizzle(blockIdx.y * gridDim.x + blockIdx.x, nwg);
    const int bm = (tile / gridDim.x) * 128, bn = (tile % gridDim.x) * 128;
    const int wr = (wid >> 1) * 64, wc = (wid & 1) * 64;

    f32x4 acc[4][4] = {};

    for (int kt = 0; kt < K; kt += 64) {
        __syncthreads();
#pragma unroll
        for (int r = 0; r < 4; ++r) {
            const int q = r * 256 + tid;
            const int row = q >> 3, c = q & 7, sc = c ^ (row & 7);
            gll16(A + (size_t)(bm + row) * K + kt + sc * 8, As + q * 8);
        }
#pragma unroll
        for (int r = 0; r < 4; ++r) {
            const int q = r * 256 + tid;
            const int row = q >> 3, c = q & 7, sc = c ^ (row & 7);
            gll16(Bt + (size_t)(bn + row) * K + kt + sc * 8, Bs + q * 8);
        }
        __syncthreads();

#pragma unroll
        for (int kk = 0; kk < 2; ++kk) {
            f16x8 af[4], bfr[4];
#pragma unroll
            for (int m = 0; m < 4; ++m) {
                const int row = wr + m * 16 + l15;
                const int ch = (kk * 4 + g) ^ (row & 7);
                af[m] = *(const f16x8*)&As[row * 64 + ch * 8];
            }
#pragma unroll
            for (int n = 0; n < 4; ++n) {
                const int row = wc + n * 16 + l15;
                const int ch = (kk * 4 + g) ^ (row & 7);
                bfr[n] = *(const f16x8*)&Bs[row * 64 + ch * 8];
            }
#pragma unroll
            for (int m = 0; m < 4; ++m)
#pragma unroll
                for (int n = 0; n < 4; ++n)
                    acc[m][n] = __builtin_amdgcn_mfma_f32_16x16x32_f16(
                        af[m], bfr[n], acc[m][n], 0, 0, 0);
        }
    }

#pragma unroll
    for (int m = 0; m < 4; ++m)
#pragma unroll
        for (int n = 0; n < 4; ++n)
#pragma unroll
            for (int r = 0; r < 4; ++r) {
                const int row = bm + wr + m * 16 + g * 4 + r;
                const int col = bn + wc + n * 16 + l15;
                const float v = acc[m][n][r];
                if (F16OUT)
                    ((unsigned short*)Cout)[(size_t)row * N + col] = f2h(v);
                else
                    ((float*)Cout)[(size_t)row * N + col] = v;
            }
}

// ---------------------------------------------------------------------------
// RMSNorm rows of 128, fp16 -> fp16, with post-scale.
// ---------------------------------------------------------------------------
__global__ __launch_bounds__(256)
void rms128_h(const unsigned short* __restrict__ in, unsigned short* __restrict__ out,
              int nrows, float post) {
    const int row  = blockIdx.x * 4 + (threadIdx.x >> 6);
    const int lane = threadIdx.x & 63;
    if (row >= nrows) return;
    const unsigned u = *(const unsigned*)(in + (size_t)row * DH + lane * 2);
    const float a = h2f((unsigned short)(u & 0xffff));
    const float b = h2f((unsigned short)(u >> 16));
    float ss = a * a + b * b;
#pragma unroll
    for (int o = 32; o >= 1; o >>= 1) ss += __shfl_xor(ss, o);
    const float sc = rsqrtf(ss * (1.f / DH) + 1.1920929e-07f) * post;
    const unsigned ov = (unsigned)f2h(a * sc) | ((unsigned)f2h(b * sc) << 16);
    *(unsigned*)(out + (size_t)row * DH + lane * 2) = ov;
}

// ---------------------------------------------------------------------------
// Build Vt[b][hk][d][t] fp16 from Vg[b*T][512] fp16 (32x32 transpose tiles)
// ---------------------------------------------------------------------------
__global__ __launch_bounds__(256)
void vt_build(const unsigned short* __restrict__ Vg, unsigned short* __restrict__ Vt) {
    __shared__ unsigned short Ls[32][36];
    const int t0 = blockIdx.x * 32;
    const int d0 = blockIdx.y * 32;
    const int bh = blockIdx.z;            // b*4 + hk
    const int b = bh >> 2, hk = bh & 3;
    const int i = threadIdx.x;
    {
        const int tr = i >> 3, d4 = (i & 7) * 4;
        const unsigned short* src = Vg + (size_t)(b * TT + t0 + tr) * KVC + hk * DH + d0 + d4;
        const unsigned u0 = *(const unsigned*)(src);
        const unsigned u1 = *(const unsigned*)(src + 2);
        Ls[tr][d4 + 0] = (unsigned short)(u0 & 0xffff);
        Ls[tr][d4 + 1] = (unsigned short)(u0 >> 16);
        Ls[tr][d4 + 2] = (unsigned short)(u1 & 0xffff);
        Ls[tr][d4 + 3] = (unsigned short)(u1 >> 16);
    }
    __syncthreads();
    {
        const int dr = i >> 3, t4 = (i & 7) * 4;
        unsigned short* dst = Vt + ((size_t)bh * DH + d0 + dr) * TT + t0 + t4;
        const unsigned o0 = (unsigned)Ls[t4 + 0][dr] | ((unsigned)Ls[t4 + 1][dr] << 16);
        const unsigned o1 = (unsigned)Ls[t4 + 2][dr] | ((unsigned)Ls[t4 + 3][dr] << 16);
        *(unsigned*)(dst)     = o0;
        *(unsigned*)(dst + 2) = o1;
    }
}

// ---------------------------------------------------------------------------
// Flash attention, fp16 32x32x16 MFMA (R9). No mask, no 1/sqrt(d) scale.
// Block: 128 thr (2 waves), 64 q-rows (32/wave). KVBLK=64.
// Rationale: 32x32 doubles MFMA FLOP per LDS byte (R8 was LDS-read bound).
// K staged [64key][128d] 4-bit XOR swizzle; Vt staged [128d][64key] 3-bit;
// P per-wave [32q][64k]. Fused in-register Q-rmsnorm*log2e. Row-sum via
// ones-column MFMA. Defer-max (log2 domain, THR=8 -> P <= 2^8, fp16-safe).
// Fragment layouts (32x32x16): A row=lane&31, k=(lane>>5)*8+j; B col=lane&31,
// k=(lane>>5)*8+j; C/D col=lane&31, row=(reg&3)+8*(reg>>2)+4*(lane>>5).
// ---------------------------------------------------------------------------
__global__ __launch_bounds__(128, 2)
void attn_mfma(const unsigned short* __restrict__ Qb, const unsigned short* __restrict__ Kb,
               const unsigned short* __restrict__ Vt, unsigned short* __restrict__ Yb) {
    __shared__ __align__(16) unsigned short Ks[64 * 128];   // [key][d] swizzled
    __shared__ __align__(16) unsigned short Vs[128 * 64];   // [d][key] swizzled
    __shared__ __align__(16) unsigned short Ps[2][32 * 64]; // per-wave [q][key]

    const int tid  = threadIdx.x;
    const int lane = tid & 63, wid = tid >> 6;          // wid 0..1
    const int l31 = lane & 31, g2 = lane >> 5;          // g2 0..1
    const int q0 = blockIdx.x * 64;
    const int bh = blockIdx.y;
    const int b = bh >> 4, h = bh & 15, hk = h >> 2;

    // ---- Q fragments: 32 q-rows/wave; lane holds dims g2*8 + f*16 + j ----
    f16x8 qf[8];
    {
        const unsigned short* qp =
            Qb + (size_t)(b * TT + q0 + wid * 32 + l31) * CC + h * DH + g2 * 8;
#pragma unroll
        for (int f = 0; f < 8; ++f) qf[f] = *(const f16x8*)(qp + f * 16);
    }
    // fused rmsnorm * log2e (lane has 64 of 128 dims; partner = lane^32)
    {
        float ss = 0.f;
#pragma unroll
        for (int f = 0; f < 8; ++f)
#pragma unroll
            for (int j = 0; j < 8; ++j) { const float v = (float)qf[f][j]; ss += v * v; }
        ss += __shfl_xor(ss, 32);
        const float qsc = rsqrtf(ss * (1.f / DH) + 1.1920929e-07f) * 1.4426950408889634f;
#pragma unroll
        for (int f = 0; f < 8; ++f)
#pragma unroll
            for (int j = 0; j < 8; ++j)
                qf[f][j] = (_Float16)((float)qf[f][j] * qsc);
    }

    // ones B-frag: col 0 only -> D col0 = row sums
    f16x8 ones_b;
    {
        const _Float16 v = (l31 == 0) ? (_Float16)1.0f : (_Float16)0.0f;
#pragma unroll
        for (int j = 0; j < 8; ++j) ones_b[j] = v;
    }

    float mr[16];
#pragma unroll
    for (int r = 0; r < 16; ++r) mr[r] = -3.0e38f;
    f32x16 accO[4] = {};
    f32x16 accl = {};

    const size_t kbase = (size_t)(b * TT) * KVC + hk * DH;
    const size_t vbase = (size_t)(b * HKV_ + hk) * DH * TT;
    unsigned short* pw = Ps[wid];

    for (int st = 0; st < TT; st += 64) {
        __syncthreads();
#pragma unroll
        for (int r = 0; r < 8; ++r) {        // K tile: 1024 16B-chunks
            const int q = r * 128 + tid;
            const int key = q >> 4, sc = q & 15, c = sc ^ (key & 15);
            gll16(Kb + kbase + (size_t)(st + key) * KVC + c * 8, Ks + q * 8);
        }
#pragma unroll
        for (int r = 0; r < 8; ++r) {        // V tile: 1024 16B-chunks
            const int q = r * 128 + tid;
            const int d = q >> 3, sc = q & 7, c = sc ^ (d & 7);
            gll16(Vt + vbase + (size_t)d * TT + st + c * 8, Vs + q * 8);
        }
        __syncthreads();

        // ---- S = Q K^T : two 32-key blocks ----
        f32x16 s0 = {}, s1 = {};
        __builtin_amdgcn_s_setprio(1);
#pragma unroll
        for (int f = 0; f < 8; ++f) {
            const int c = f * 2 + g2;
            const f16x8 k0 = *(const f16x8*)&Ks[l31 * 128 + (c ^ (l31 & 15)) * 8];
            const f16x8 k1 = *(const f16x8*)&Ks[(32 + l31) * 128 + (c ^ (l31 & 15)) * 8];
            s0 = __builtin_amdgcn_mfma_f32_32x32x16_f16(qf[f], k0, s0, 0, 0, 0);
            s1 = __builtin_amdgcn_mfma_f32_32x32x16_f16(qf[f], k1, s1, 0, 0, 0);
        }
        __builtin_amdgcn_s_setprio(0);

        // ---- defer-max: shuffle-free common path ----
        float pm[16];
        bool need = false;
#pragma unroll
        for (int r = 0; r < 16; ++r) {
            pm[r] = fmaxf(s0[r], s1[r]);
            need = need || (pm[r] > mr[r] + 8.f);
        }
        if (__any(need)) {
            float scl[16];
#pragma unroll
            for (int r = 0; r < 16; ++r) {
                float mx = pm[r];
#pragma unroll
                for (int o = 16; o >= 1; o >>= 1) mx = fmaxf(mx, __shfl_xor(mx, o));
                const float mn = fmaxf(mr[r], mx);
                scl[r] = __builtin_amdgcn_exp2f(mr[r] - mn);
                mr[r] = mn;
            }
#pragma unroll
            for (int r = 0; r < 16; ++r) {
                accO[0][r] *= scl[r]; accO[1][r] *= scl[r];
                accO[2][r] *= scl[r]; accO[3][r] *= scl[r];
                accl[r] *= scl[r];
            }
        }

        // ---- P = exp2(S - m) -> per-wave LDS (swizzled) ----
#pragma unroll
        for (int r = 0; r < 16; ++r) {
            const float p0 = __builtin_amdgcn_exp2f(s0[r] - mr[r]);
            const float p1 = __builtin_amdgcn_exp2f(s1[r] - mr[r]);
            const int qrow = (r & 3) + 8 * (r >> 2) + 4 * g2;
            const int c0 = l31 >> 3, c1 = 4 + (l31 >> 3);
            pw[qrow * 64 + ((c0 ^ (qrow & 7)) * 8) + (l31 & 7)] = f2h(p0);
            pw[qrow * 64 + ((c1 ^ (qrow & 7)) * 8) + (l31 & 7)] = f2h(p1);
        }

        // ---- O += P V ; l += P 1 ----
        __builtin_amdgcn_s_setprio(1);
#pragma unroll
        for (int ks = 0; ks < 4; ++ks) {
            const int c = ks * 2 + g2;
            const f16x8 pa = *(const f16x8*)&pw[l31 * 64 + ((c ^ (l31 & 7)) * 8)];
#pragma unroll
            for (int db = 0; db < 4; ++db) {
                const int d = db * 32 + l31;
                const f16x8 vf = *(const f16x8*)&Vs[d * 64 + ((c ^ (d & 7)) * 8)];
                accO[db] = __builtin_amdgcn_mfma_f32_32x32x16_f16(pa, vf, accO[db], 0, 0, 0);
            }
            accl = __builtin_amdgcn_mfma_f32_32x32x16_f16(pa, ones_b, accl, 0, 0, 0);
        }
        __builtin_amdgcn_s_setprio(0);
    }

    // ---- finalize: l at col0 (lane g2*32), divide, store ----
    float inv[16];
#pragma unroll
    for (int r = 0; r < 16; ++r) {
        const float l = __shfl(accl[r], g2 * 32);
        inv[r] = 1.f / l;
    }
#pragma unroll
    for (int db = 0; db < 4; ++db)
#pragma unroll
        for (int r = 0; r < 16; ++r) {
            const int qrow = (r & 3) + 8 * (r >> 2) + 4 * g2;
            const int t = q0 + wid * 32 + qrow;
            const int col = h * DH + db * 32 + l31;
            Yb[(size_t)(b * TT + t) * CC + col] = f2h(accO[db][r] * inv[r]);
        }
}

// ---------------------------------------------------------------------------
// RMSNorm rows of 2048, fp32 in-place (final output norm)
// ---------------------------------------------------------------------------
__global__ __launch_bounds__(256)
void rms2048_inplace(float* __restrict__ d) {
    __shared__ float red[4];
    const int tid = threadIdx.x;
    float* p = d + (size_t)blockIdx.x * CC;
    float4 a = *(float4*)&p[tid * 8];
    float4 b = *(float4*)&p[tid * 8 + 4];
    float ss = a.x * a.x + a.y * a.y + a.z * a.z + a.w * a.w +
               b.x * b.x + b.y * b.y + b.z * b.z + b.w * b.w;
#pragma unroll
    for (int o = 32; o >= 1; o >>= 1) ss += __shfl_xor(ss, o);
    if ((tid & 63) == 0) red[tid >> 6] = ss;
    __syncthreads();
    const float tot = red[0] + red[1] + red[2] + red[3];
    const float sc = rsqrtf(tot * (1.f / CC) + 1.1920929e-07f);
    a.x *= sc; a.y *= sc; a.z *= sc; a.w *= sc;
    b.x *= sc; b.y *= sc; b.z *= sc; b.w *= sc;
    *(float4*)&p[tid * 8]     = a;
    *(float4*)&p[tid * 8 + 4] = b;
}

// ---------------------------------------------------------------------------
extern "C" void kernel_launch(void* const* d_in, const int* in_sizes, int n_in,
                              void* d_out, int out_size, void* d_ws, size_t ws_size,
                              hipStream_t stream) {
    const float* x  = (const float*)d_in[0];
    const float* Wq = (const float*)d_in[1];
    // d_in[2] = Wk — unused by the reference (K = rmsnorm(V))
    const float* Wv = (const float*)d_in[3];
    const float* Wo = (const float*)d_in[4];
    float* out = (float*)d_out;

    char* ws = (char*)d_ws;
    const size_t MB = 1024 * 1024;
    unsigned short* xb  = (unsigned short*)(ws);             // 16 MB
    unsigned short* WqT = (unsigned short*)(ws + 16 * MB);   //  8 MB
    unsigned short* WoT = WqT;                               // reuse after gemm Q
    unsigned short* WvT = (unsigned short*)(ws + 24 * MB);   //  2 MB
    unsigned short* Qg  = (unsigned short*)(ws + 26 * MB);   // 16 MB (raw Q, normed in attn)
    unsigned short* Vg  = (unsigned short*)(ws + 42 * MB);   //  4 MB
    unsigned short* Kb  = (unsigned short*)(ws + 46 * MB);   //  4 MB
    unsigned short* Vt  = (unsigned short*)(ws + 50 * MB);   //  4 MB
    unsigned short* Yb  = (unsigned short*)(ws + 54 * MB);   // 16 MB  (peak 70 MB)

    const dim3 blk(256);

    cast_f16<<<2048, blk, 0, stream>>>(x, xb, MM * CC / 8);
    tcast<<<dim3(CC / 32, CC / 32), blk, 0, stream>>>(Wq, WqT, CC, CC);
    tcast<<<dim3(KVC / 32, CC / 32), blk, 0, stream>>>(Wv, WvT, CC, KVC);

    gemm_bt<1><<<dim3(CC / 128, MM / 128), blk, 0, stream>>>(xb, WqT, Qg, MM, CC, CC);
    gemm_bt<1><<<dim3(KVC / 128, MM / 128), blk, 0, stream>>>(xb, WvT, Vg, MM, KVC, CC);

    tcast<<<dim3(CC / 32, CC / 32), blk, 0, stream>>>(Wo, WoT, CC, CC);  // after gemm Q

    rms128_h<<<MM * HKV_ / 4, blk, 0, stream>>>(Vg, Kb, MM * HKV_, 1.f); // K = norm(V)
    vt_build<<<dim3(TT / 32, DH / 32, BB * HKV_), blk, 0, stream>>>(Vg, Vt);

    attn_mfma<<<dim3(TT / 64, BB * HQ_), dim3(128), 0, stream>>>(Qg, Kb, Vt, Yb);

    gemm_bt<0><<<dim3(CC / 128, MM / 128), blk, 0, stream>>>(Yb, WoT, out, MM, CC, CC);
    rms2048_inplace<<<MM, blk, 0, stream>>>(out);
}

// Round 10
// 336.315 us; speedup vs baseline: 1.0809x; 1.0809x over previous
//
#include <hip/hip_runtime.h>
#include <math.h>

// Problem constants (B=2, T=2048, C=2048, HQ=16, HKV=4, Dh=128, WIN=256)
#define BB   2
#define TT   2048
#define CC   2048
#define HQ_  16
#define HKV_ 4
#define DH   128
#define MM   (BB * TT)          // 4096 rows
#define KVC  (HKV_ * DH)        // 512

typedef __attribute__((ext_vector_type(8)))  _Float16 f16x8;
typedef __attribute__((ext_vector_type(4)))  float    f32x4;
typedef __attribute__((ext_vector_type(16))) float    f32x16;

__device__ __forceinline__ unsigned short f2h(float x) {
    _Float16 h = (_Float16)x;                 // RNE v_cvt_f16_f32
    return __builtin_bit_cast(unsigned short, h);
}
__device__ __forceinline__ float h2f(unsigned short u) {
    return (float)__builtin_bit_cast(_Float16, u);
}
__device__ __forceinline__ void gll16(const void* g, void* l) {
    __builtin_amdgcn_global_load_lds(
        (const __attribute__((address_space(1))) unsigned int*)g,
        (__attribute__((address_space(3))) unsigned int*)l, 16, 0, 0);
}
// bijective XCD-aware tile remap (T1, m204 form).
__device__ __forceinline__ int xcd_swizzle(int lid, int nwg) {
    const int xcd = lid & 7, rank = lid >> 3;
    const int q8 = nwg >> 3, r8 = nwg & 7;
    return (xcd < r8 ? xcd * (q8 + 1) : r8 * (q8 + 1) + (xcd - r8) * q8) + rank;
}

// ---------------------------------------------------------------------------
// fp32 -> fp16 cast, 8 elems/thread
// ---------------------------------------------------------------------------
__global__ __launch_bounds__(256)
void cast_f16(const float* __restrict__ in, unsigned short* __restrict__ out, int n8) {
    int i = blockIdx.x * blockDim.x + threadIdx.x;
    const int stride = gridDim.x * blockDim.x;
    for (; i < n8; i += stride) {
        const float4 a = ((const float4*)in)[i * 2 + 0];
        const float4 b = ((const float4*)in)[i * 2 + 1];
        uint4 o;
        o.x = (unsigned)f2h(a.x) | ((unsigned)f2h(a.y) << 16);
        o.y = (unsigned)f2h(a.z) | ((unsigned)f2h(a.w) << 16);
        o.z = (unsigned)f2h(b.x) | ((unsigned)f2h(b.y) << 16);
        o.w = (unsigned)f2h(b.z) | ((unsigned)f2h(b.w) << 16);
        ((uint4*)out)[i] = o;
    }
}

// ---------------------------------------------------------------------------
// Transpose-cast: W[Kd][Nd] fp32 -> WT[Nd][Kd] fp16. 32x32 tiles.
// ---------------------------------------------------------------------------
__global__ __launch_bounds__(256)
void tcast(const float* __restrict__ W, unsigned short* __restrict__ WT, int Kd, int Nd) {
    __shared__ float Ls[32][33];
    const int n0 = blockIdx.x * 32, k0 = blockIdx.y * 32;
    const int i = threadIdx.x;
    {
        const int kr = i >> 3, n4 = (i & 7) * 4;
        float4 v = *(const float4*)&W[(size_t)(k0 + kr) * Nd + n0 + n4];
        Ls[kr][n4 + 0] = v.x; Ls[kr][n4 + 1] = v.y;
        Ls[kr][n4 + 2] = v.z; Ls[kr][n4 + 3] = v.w;
    }
    __syncthreads();
    {
        const int nr = i >> 3, k4 = (i & 7) * 4;
        uint2 o;
        o.x = (unsigned)f2h(Ls[k4 + 0][nr]) | ((unsigned)f2h(Ls[k4 + 1][nr]) << 16);
        o.y = (unsigned)f2h(Ls[k4 + 2][nr]) | ((unsigned)f2h(Ls[k4 + 3][nr]) << 16);
        *(uint2*)&WT[(size_t)(n0 + nr) * Kd + k0 + k4] = o;
    }
}

// ---------------------------------------------------------------------------
// fp16 MFMA GEMM, B^T input: C[M][N] = A[M][K] * Bt[N][K]^T
// 128x128 tile, BK=64, 4 waves, global_load_lds staging, XOR chunk-swizzle,
// XCD-aware tile swizzle (T1).
// ---------------------------------------------------------------------------
template<int F16OUT>
__global__ __launch_bounds__(256)
void gemm_bt(const unsigned short* __restrict__ A, const unsigned short* __restrict__ Bt,
             void* __restrict__ Cout, int M, int N, int K) {
    __shared__ __align__(16) unsigned short As[128 * 64];
    __shared__ __align__(16) unsigned short Bs[128 * 64];
    const int tid  = threadIdx.x;
    const int lane = tid & 63, wid = tid >> 6;
    const int g = lane >> 4, l15 = lane & 15;
    const int nwg  = gridDim.x * gridDim.y;
    const int tile = xcd_swizzle(blockIdx.y * gridDim.x + blockIdx.x, nwg);
    const int bm = (tile / gridDim.x) * 128, bn = (tile % gridDim.x) * 128;
    const int wr = (wid >> 1) * 64, wc = (wid & 1) * 64;

    f32x4 acc[4][4] = {};

    for (int kt = 0; kt < K; kt += 64) {
        __syncthreads();
#pragma unroll
        for (int r = 0; r < 4; ++r) {
            const int q = r * 256 + tid;
            const int row = q >> 3, c = q & 7, sc = c ^ (row & 7);
            gll16(A + (size_t)(bm + row) * K + kt + sc * 8, As + q * 8);
        }
#pragma unroll
        for (int r = 0; r < 4; ++r) {
            const int q = r * 256 + tid;
            const int row = q >> 3, c = q & 7, sc = c ^ (row & 7);
            gll16(Bt + (size_t)(bn + row) * K + kt + sc * 8, Bs + q * 8);
        }
        __syncthreads();

#pragma unroll
        for (int kk = 0; kk < 2; ++kk) {
            f16x8 af[4], bfr[4];
#pragma unroll
            for (int m = 0; m < 4; ++m) {
                const int row = wr + m * 16 + l15;
                const int ch = (kk * 4 + g) ^ (row & 7);
                af[m] = *(const f16x8*)&As[row * 64 + ch * 8];
            }
#pragma unroll
            for (int n = 0; n < 4; ++n) {
                const int row = wc + n * 16 + l15;
                const int ch = (kk * 4 + g) ^ (row & 7);
                bfr[n] = *(const f16x8*)&Bs[row * 64 + ch * 8];
            }
#pragma unroll
            for (int m = 0; m < 4; ++m)
#pragma unroll
                for (int n = 0; n < 4; ++n)
                    acc[m][n] = __builtin_amdgcn_mfma_f32_16x16x32_f16(
                        af[m], bfr[n], acc[m][n], 0, 0, 0);
        }
    }

#pragma unroll
    for (int m = 0; m < 4; ++m)
#pragma unroll
        for (int n = 0; n < 4; ++n)
#pragma unroll
            for (int r = 0; r < 4; ++r) {
                const int row = bm + wr + m * 16 + g * 4 + r;
                const int col = bn + wc + n * 16 + l15;
                const float v = acc[m][n][r];
                if (F16OUT)
                    ((unsigned short*)Cout)[(size_t)row * N + col] = f2h(v);
                else
                    ((float*)Cout)[(size_t)row * N + col] = v;
            }
}

// ---------------------------------------------------------------------------
// RMSNorm rows of 128, fp16 -> fp16, with post-scale.
// ---------------------------------------------------------------------------
__global__ __launch_bounds__(256)
void rms128_h(const unsigned short* __restrict__ in, unsigned short* __restrict__ out,
              int nrows, float post) {
    const int row  = blockIdx.x * 4 + (threadIdx.x >> 6);
    const int lane = threadIdx.x & 63;
    if (row >= nrows) return;
    const unsigned u = *(const unsigned*)(in + (size_t)row * DH + lane * 2);
    const float a = h2f((unsigned short)(u & 0xffff));
    const float b = h2f((unsigned short)(u >> 16));
    float ss = a * a + b * b;
#pragma unroll
    for (int o = 32; o >= 1; o >>= 1) ss += __shfl_xor(ss, o);
    const float sc = rsqrtf(ss * (1.f / DH) + 1.1920929e-07f) * post;
    const unsigned ov = (unsigned)f2h(a * sc) | ((unsigned)f2h(b * sc) << 16);
    *(unsigned*)(out + (size_t)row * DH + lane * 2) = ov;
}

// ---------------------------------------------------------------------------
// Build Vt[b][hk][d][t] fp16 from Vg[b*T][512] fp16 (32x32 transpose tiles)
// ---------------------------------------------------------------------------
__global__ __launch_bounds__(256)
void vt_build(const unsigned short* __restrict__ Vg, unsigned short* __restrict__ Vt) {
    __shared__ unsigned short Ls[32][36];
    const int t0 = blockIdx.x * 32;
    const int d0 = blockIdx.y * 32;
    const int bh = blockIdx.z;            // b*4 + hk
    const int b = bh >> 2, hk = bh & 3;
    const int i = threadIdx.x;
    {
        const int tr = i >> 3, d4 = (i & 7) * 4;
        const unsigned short* src = Vg + (size_t)(b * TT + t0 + tr) * KVC + hk * DH + d0 + d4;
        const unsigned u0 = *(const unsigned*)(src);
        const unsigned u1 = *(const unsigned*)(src + 2);
        Ls[tr][d4 + 0] = (unsigned short)(u0 & 0xffff);
        Ls[tr][d4 + 1] = (unsigned short)(u0 >> 16);
        Ls[tr][d4 + 2] = (unsigned short)(u1 & 0xffff);
        Ls[tr][d4 + 3] = (unsigned short)(u1 >> 16);
    }
    __syncthreads();
    {
        const int dr = i >> 3, t4 = (i & 7) * 4;
        unsigned short* dst = Vt + ((size_t)bh * DH + d0 + dr) * TT + t0 + t4;
        const unsigned o0 = (unsigned)Ls[t4 + 0][dr] | ((unsigned)Ls[t4 + 1][dr] << 16);
        const unsigned o1 = (unsigned)Ls[t4 + 2][dr] | ((unsigned)Ls[t4 + 3][dr] << 16);
        *(unsigned*)(dst)     = o0;
        *(unsigned*)(dst + 2) = o1;
    }
}

// ---------------------------------------------------------------------------
// Flash attention, fp16 32x32x16 MFMA (R10). No mask, no 1/sqrt(d) scale.
// Geometry fix vs R9: 4 waves x 32 q-rows = 128-row blocks (grid 512),
// double-buffered K/V (KVBLK=64, 80KB LDS, 2 blocks/CU -- grid-capped anyway,
// so dbuf costs nothing and removes the per-tile staging drain).
// All fragment layouts identical to R9 (numerically validated there).
// ---------------------------------------------------------------------------
__global__ __launch_bounds__(256, 2)
void attn_mfma(const unsigned short* __restrict__ Qb, const unsigned short* __restrict__ Kb,
               const unsigned short* __restrict__ Vt, unsigned short* __restrict__ Yb) {
    __shared__ __align__(16) unsigned short Ks[2][64 * 128];   // [key][d] swizzled
    __shared__ __align__(16) unsigned short Vs[2][128 * 64];   // [d][key] swizzled
    __shared__ __align__(16) unsigned short Ps[4][32 * 64];    // per-wave [q][key]

    const int tid  = threadIdx.x;
    const int lane = tid & 63, wid = tid >> 6;          // wid 0..3
    const int l31 = lane & 31, g2 = lane >> 5;          // g2 0..1
    const int q0 = blockIdx.x * 128;
    const int bh = blockIdx.y;
    const int b = bh >> 4, h = bh & 15, hk = h >> 2;

    const size_t kbase = (size_t)(b * TT) * KVC + hk * DH;
    const size_t vbase = (size_t)(b * HKV_ + hk) * DH * TT;

    // stage a 64-key K/V tile into buffer `buf` (8 gll16 per thread)
#define STAGE(buf, st)                                                         \
    do {                                                                       \
        _Pragma("unroll")                                                      \
        for (int r = 0; r < 4; ++r) {                                          \
            const int qq = r * 256 + tid;                                      \
            const int key = qq >> 4, c = qq & 15, sc = c ^ (key & 15);         \
            gll16(Kb + kbase + (size_t)((st) + key) * KVC + sc * 8,            \
                  &Ks[buf][qq * 8]);                                           \
        }                                                                      \
        _Pragma("unroll")                                                      \
        for (int r = 0; r < 4; ++r) {                                          \
            const int qq = r * 256 + tid;                                      \
            const int d = qq >> 3, c = qq & 7, sc = c ^ (d & 7);               \
            gll16(Vt + vbase + (size_t)d * TT + (st) + sc * 8,                 \
                  &Vs[buf][qq * 8]);                                           \
        }                                                                      \
    } while (0)

    STAGE(0, 0);   // prologue: tile 0 in flight while we load/norm Q

    // ---- Q fragments: 32 q-rows/wave; lane holds dims g2*8 + f*16 + j ----
    f16x8 qf[8];
    {
        const unsigned short* qp =
            Qb + (size_t)(b * TT + q0 + wid * 32 + l31) * CC + h * DH + g2 * 8;
#pragma unroll
        for (int f = 0; f < 8; ++f) qf[f] = *(const f16x8*)(qp + f * 16);
    }
    // fused rmsnorm * log2e (lane has 64 of 128 dims; partner = lane^32)
    {
        float ss = 0.f;
#pragma unroll
        for (int f = 0; f < 8; ++f)
#pragma unroll
            for (int j = 0; j < 8; ++j) { const float v = (float)qf[f][j]; ss += v * v; }
        ss += __shfl_xor(ss, 32);
        const float qsc = rsqrtf(ss * (1.f / DH) + 1.1920929e-07f) * 1.4426950408889634f;
#pragma unroll
        for (int f = 0; f < 8; ++f)
#pragma unroll
            for (int j = 0; j < 8; ++j)
                qf[f][j] = (_Float16)((float)qf[f][j] * qsc);
    }

    // ones B-frag: col 0 only -> D col0 = row sums
    f16x8 ones_b;
    {
        const _Float16 v = (l31 == 0) ? (_Float16)1.0f : (_Float16)0.0f;
#pragma unroll
        for (int j = 0; j < 8; ++j) ones_b[j] = v;
    }

    float mr[16];
#pragma unroll
    for (int r = 0; r < 16; ++r) mr[r] = -3.0e38f;
    f32x16 accO[4] = {};
    f32x16 accl = {};

    unsigned short* pw = Ps[wid];

    asm volatile("s_waitcnt vmcnt(0)" ::: "memory");
    __builtin_amdgcn_s_barrier();

    const int NT = TT / 64;   // 32 tiles
    for (int t = 0; t < NT; ++t) {
        const int cur = t & 1;
        if (t + 1 < NT) STAGE(cur ^ 1, (t + 1) * 64);   // prefetch next tile

        const unsigned short* ksp = Ks[cur];
        const unsigned short* vsp = Vs[cur];

        // ---- S = Q K^T : two 32-key blocks ----
        f32x16 s0 = {}, s1 = {};
        __builtin_amdgcn_s_setprio(1);
#pragma unroll
        for (int f = 0; f < 8; ++f) {
            const int c = f * 2 + g2;
            const f16x8 k0 = *(const f16x8*)&ksp[l31 * 128 + ((c ^ (l31 & 15)) * 8)];
            const f16x8 k1 = *(const f16x8*)&ksp[(32 + l31) * 128 + ((c ^ (l31 & 15)) * 8)];
            s0 = __builtin_amdgcn_mfma_f32_32x32x16_f16(qf[f], k0, s0, 0, 0, 0);
            s1 = __builtin_amdgcn_mfma_f32_32x32x16_f16(qf[f], k1, s1, 0, 0, 0);
        }
        __builtin_amdgcn_s_setprio(0);

        // ---- defer-max: shuffle-free common path ----
        float pm[16];
        bool need = false;
#pragma unroll
        for (int r = 0; r < 16; ++r) {
            pm[r] = fmaxf(s0[r], s1[r]);
            need = need || (pm[r] > mr[r] + 8.f);
        }
        if (__any(need)) {
            float scl[16];
#pragma unroll
            for (int r = 0; r < 16; ++r) {
                float mx = pm[r];
#pragma unroll
                for (int o = 16; o >= 1; o >>= 1) mx = fmaxf(mx, __shfl_xor(mx, o));
                const float mn = fmaxf(mr[r], mx);
                scl[r] = __builtin_amdgcn_exp2f(mr[r] - mn);
                mr[r] = mn;
            }
#pragma unroll
            for (int r = 0; r < 16; ++r) {
                accO[0][r] *= scl[r]; accO[1][r] *= scl[r];
                accO[2][r] *= scl[r]; accO[3][r] *= scl[r];
                accl[r] *= scl[r];
            }
        }

        // ---- P = exp2(S - m) -> per-wave LDS (swizzled) ----
#pragma unroll
        for (int r = 0; r < 16; ++r) {
            const float p0 = __builtin_amdgcn_exp2f(s0[r] - mr[r]);
            const float p1 = __builtin_amdgcn_exp2f(s1[r] - mr[r]);
            const int qrow = (r & 3) + 8 * (r >> 2) + 4 * g2;
            const int c0 = l31 >> 3, c1 = 4 + (l31 >> 3);
            pw[qrow * 64 + ((c0 ^ (qrow & 7)) * 8) + (l31 & 7)] = f2h(p0);
            pw[qrow * 64 + ((c1 ^ (qrow & 7)) * 8) + (l31 & 7)] = f2h(p1);
        }

        // ---- O += P V ; l += P 1 ----
        __builtin_amdgcn_s_setprio(1);
#pragma unroll
        for (int ks = 0; ks < 4; ++ks) {
            const int c = ks * 2 + g2;
            const f16x8 pa = *(const f16x8*)&pw[l31 * 64 + ((c ^ (l31 & 7)) * 8)];
#pragma unroll
            for (int db = 0; db < 4; ++db) {
                const int d = db * 32 + l31;
                const f16x8 vf = *(const f16x8*)&vsp[d * 64 + ((c ^ (d & 7)) * 8)];
                accO[db] = __builtin_amdgcn_mfma_f32_32x32x16_f16(pa, vf, accO[db], 0, 0, 0);
            }
            accl = __builtin_amdgcn_mfma_f32_32x32x16_f16(pa, ones_b, accl, 0, 0, 0);
        }
        __builtin_amdgcn_s_setprio(0);

        // next tile's loads have had the whole compute phase to land
        asm volatile("s_waitcnt vmcnt(0)" ::: "memory");
        __builtin_amdgcn_s_barrier();
    }
#undef STAGE

    // ---- finalize: l at col0 (lane g2*32), divide, store ----
    float inv[16];
#pragma unroll
    for (int r = 0; r < 16; ++r) {
        const float l = __shfl(accl[r], g2 * 32);
        inv[r] = 1.f / l;
    }
#pragma unroll
    for (int db = 0; db < 4; ++db)
#pragma unroll
        for (int r = 0; r < 16; ++r) {
            const int qrow = (r & 3) + 8 * (r >> 2) + 4 * g2;
            const int t = q0 + wid * 32 + qrow;
            const int col = h * DH + db * 32 + l31;
            Yb[(size_t)(b * TT + t) * CC + col] = f2h(accO[db][r] * inv[r]);
        }
}

// ---------------------------------------------------------------------------
// RMSNorm rows of 2048, fp32 in-place (final output norm)
// ---------------------------------------------------------------------------
__global__ __launch_bounds__(256)
void rms2048_inplace(float* __restrict__ d) {
    __shared__ float red[4];
    const int tid = threadIdx.x;
    float* p = d + (size_t)blockIdx.x * CC;
    float4 a = *(float4*)&p[tid * 8];
    float4 b = *(float4*)&p[tid * 8 + 4];
    float ss = a.x * a.x + a.y * a.y + a.z * a.z + a.w * a.w +
               b.x * b.x + b.y * b.y + b.z * b.z + b.w * b.w;
#pragma unroll
    for (int o = 32; o >= 1; o >>= 1) ss += __shfl_xor(ss, o);
    if ((tid & 63) == 0) red[tid >> 6] = ss;
    __syncthreads();
    const float tot = red[0] + red[1] + red[2] + red[3];
    const float sc = rsqrtf(tot * (1.f / CC) + 1.1920929e-07f);
    a.x *= sc; a.y *= sc; a.z *= sc; a.w *= sc;
    b.x *= sc; b.y *= sc; b.z *= sc; b.w *= sc;
    *(float4*)&p[tid * 8]     = a;
    *(float4*)&p[tid * 8 + 4] = b;
}

// ---------------------------------------------------------------------------
extern "C" void kernel_launch(void* const* d_in, const int* in_sizes, int n_in,
                              void* d_out, int out_size, void* d_ws, size_t ws_size,
                              hipStream_t stream) {
    const float* x  = (const float*)d_in[0];
    const float* Wq = (const float*)d_in[1];
    // d_in[2] = Wk — unused by the reference (K = rmsnorm(V))
    const float* Wv = (const float*)d_in[3];
    const float* Wo = (const float*)d_in[4];
    float* out = (float*)d_out;

    char* ws = (char*)d_ws;
    const size_t MB = 1024 * 1024;
    unsigned short* xb  = (unsigned short*)(ws);             // 16 MB
    unsigned short* WqT = (unsigned short*)(ws + 16 * MB);   //  8 MB
    unsigned short* WoT = WqT;                               // reuse after gemm Q
    unsigned short* WvT = (unsigned short*)(ws + 24 * MB);   //  2 MB
    unsigned short* Qg  = (unsigned short*)(ws + 26 * MB);   // 16 MB (raw Q, normed in attn)
    unsigned short* Vg  = (unsigned short*)(ws + 42 * MB);   //  4 MB
    unsigned short* Kb  = (unsigned short*)(ws + 46 * MB);   //  4 MB
    unsigned short* Vt  = (unsigned short*)(ws + 50 * MB);   //  4 MB
    unsigned short* Yb  = (unsigned short*)(ws + 54 * MB);   // 16 MB  (peak 70 MB)

    const dim3 blk(256);

    cast_f16<<<2048, blk, 0, stream>>>(x, xb, MM * CC / 8);
    tcast<<<dim3(CC / 32, CC / 32), blk, 0, stream>>>(Wq, WqT, CC, CC);
    tcast<<<dim3(KVC / 32, CC / 32), blk, 0, stream>>>(Wv, WvT, CC, KVC);

    gemm_bt<1><<<dim3(CC / 128, MM / 128), blk, 0, stream>>>(xb, WqT, Qg, MM, CC, CC);
    gemm_bt<1><<<dim3(KVC / 128, MM / 128), blk, 0, stream>>>(xb, WvT, Vg, MM, KVC, CC);

    tcast<<<dim3(CC / 32, CC / 32), blk, 0, stream>>>(Wo, WoT, CC, CC);  // after gemm Q

    rms128_h<<<MM * HKV_ / 4, blk, 0, stream>>>(Vg, Kb, MM * HKV_, 1.f); // K = norm(V)
    vt_build<<<dim3(TT / 32, DH / 32, BB * HKV_), blk, 0, stream>>>(Vg, Vt);

    attn_mfma<<<dim3(TT / 128, BB * HQ_), blk, 0, stream>>>(Qg, Kb, Vt, Yb);

    gemm_bt<0><<<dim3(CC / 128, MM / 128), blk, 0, stream>>>(Yb, WoT, out, MM, CC, CC);
    rms2048_inplace<<<MM, blk, 0, stream>>>(out);
}

// Round 11
// 288.424 us; speedup vs baseline: 1.2603x; 1.1660x over previous
//
#include <hip/hip_runtime.h>
#include <math.h>

// Problem constants (B=2, T=2048, C=2048, HQ=16, HKV=4, Dh=128, WIN=256)
#define BB   2
#define TT   2048
#define CC   2048
#define HQ_  16
#define HKV_ 4
#define DH   128
#define MM   (BB * TT)          // 4096 rows
#define KVC  (HKV_ * DH)        // 512

typedef __attribute__((ext_vector_type(8)))  _Float16 f16x8;
typedef __attribute__((ext_vector_type(4)))  float    f32x4;

__device__ __forceinline__ unsigned short f2h(float x) {
    _Float16 h = (_Float16)x;                 // RNE v_cvt_f16_f32
    return __builtin_bit_cast(unsigned short, h);
}
__device__ __forceinline__ float h2f(unsigned short u) {
    return (float)__builtin_bit_cast(_Float16, u);
}
__device__ __forceinline__ void gll16(const void* g, void* l) {
    __builtin_amdgcn_global_load_lds(
        (const __attribute__((address_space(1))) unsigned int*)g,
        (__attribute__((address_space(3))) unsigned int*)l, 16, 0, 0);
}
// bijective XCD-aware tile remap (T1, m204 form).
__device__ __forceinline__ int xcd_swizzle(int lid, int nwg) {
    const int xcd = lid & 7, rank = lid >> 3;
    const int q8 = nwg >> 3, r8 = nwg & 7;
    return (xcd < r8 ? xcd * (q8 + 1) : r8 * (q8 + 1) + (xcd - r8) * q8) + rank;
}

// ---------------------------------------------------------------------------
// fp32 -> fp16 cast, 8 elems/thread
// ---------------------------------------------------------------------------
__global__ __launch_bounds__(256)
void cast_f16(const float* __restrict__ in, unsigned short* __restrict__ out, int n8) {
    int i = blockIdx.x * blockDim.x + threadIdx.x;
    const int stride = gridDim.x * blockDim.x;
    for (; i < n8; i += stride) {
        const float4 a = ((const float4*)in)[i * 2 + 0];
        const float4 b = ((const float4*)in)[i * 2 + 1];
        uint4 o;
        o.x = (unsigned)f2h(a.x) | ((unsigned)f2h(a.y) << 16);
        o.y = (unsigned)f2h(a.z) | ((unsigned)f2h(a.w) << 16);
        o.z = (unsigned)f2h(b.x) | ((unsigned)f2h(b.y) << 16);
        o.w = (unsigned)f2h(b.z) | ((unsigned)f2h(b.w) << 16);
        ((uint4*)out)[i] = o;
    }
}

// ---------------------------------------------------------------------------
// Transpose-cast: W[Kd][Nd] fp32 -> WT[Nd][Kd] fp16. 32x32 tiles.
// ---------------------------------------------------------------------------
__global__ __launch_bounds__(256)
void tcast(const float* __restrict__ W, unsigned short* __restrict__ WT, int Kd, int Nd) {
    __shared__ float Ls[32][33];
    const int n0 = blockIdx.x * 32, k0 = blockIdx.y * 32;
    const int i = threadIdx.x;
    {
        const int kr = i >> 3, n4 = (i & 7) * 4;
        float4 v = *(const float4*)&W[(size_t)(k0 + kr) * Nd + n0 + n4];
        Ls[kr][n4 + 0] = v.x; Ls[kr][n4 + 1] = v.y;
        Ls[kr][n4 + 2] = v.z; Ls[kr][n4 + 3] = v.w;
    }
    __syncthreads();
    {
        const int nr = i >> 3, k4 = (i & 7) * 4;
        uint2 o;
        o.x = (unsigned)f2h(Ls[k4 + 0][nr]) | ((unsigned)f2h(Ls[k4 + 1][nr]) << 16);
        o.y = (unsigned)f2h(Ls[k4 + 2][nr]) | ((unsigned)f2h(Ls[k4 + 3][nr]) << 16);
        *(uint2*)&WT[(size_t)(n0 + nr) * Kd + k0 + k4] = o;
    }
}

// ---------------------------------------------------------------------------
// fp16 MFMA GEMM, B^T input: C[M][N] = A[M][K] * Bt[N][K]^T
// 128x128 tile, BK=64, 4 waves, global_load_lds staging, XOR chunk-swizzle,
// XCD-aware tile swizzle (T1).
// ---------------------------------------------------------------------------
template<int F16OUT>
__global__ __launch_bounds__(256)
void gemm_bt(const unsigned short* __restrict__ A, const unsigned short* __restrict__ Bt,
             void* __restrict__ Cout, int M, int N, int K) {
    __shared__ __align__(16) unsigned short As[128 * 64];
    __shared__ __align__(16) unsigned short Bs[128 * 64];
    const int tid  = threadIdx.x;
    const int lane = tid & 63, wid = tid >> 6;
    const int g = lane >> 4, l15 = lane & 15;
    const int nwg  = gridDim.x * gridDim.y;
    const int tile = xcd_swizzle(blockIdx.y * gridDim.x + blockIdx.x, nwg);
    const int bm = (tile / gridDim.x) * 128, bn = (tile % gridDim.x) * 128;
    const int wr = (wid >> 1) * 64, wc = (wid & 1) * 64;

    f32x4 acc[4][4] = {};

    for (int kt = 0; kt < K; kt += 64) {
        __syncthreads();
#pragma unroll
        for (int r = 0; r < 4; ++r) {
            const int q = r * 256 + tid;
            const int row = q >> 3, c = q & 7, sc = c ^ (row & 7);
            gll16(A + (size_t)(bm + row) * K + kt + sc * 8, As + q * 8);
        }
#pragma unroll
        for (int r = 0; r < 4; ++r) {
            const int q = r * 256 + tid;
            const int row = q >> 3, c = q & 7, sc = c ^ (row & 7);
            gll16(Bt + (size_t)(bn + row) * K + kt + sc * 8, Bs + q * 8);
        }
        __syncthreads();

#pragma unroll
        for (int kk = 0; kk < 2; ++kk) {
            f16x8 af[4], bfr[4];
#pragma unroll
            for (int m = 0; m < 4; ++m) {
                const int row = wr + m * 16 + l15;
                const int ch = (kk * 4 + g) ^ (row & 7);
                af[m] = *(const f16x8*)&As[row * 64 + ch * 8];
            }
#pragma unroll
            for (int n = 0; n < 4; ++n) {
                const int row = wc + n * 16 + l15;
                const int ch = (kk * 4 + g) ^ (row & 7);
                bfr[n] = *(const f16x8*)&Bs[row * 64 + ch * 8];
            }
#pragma unroll
            for (int m = 0; m < 4; ++m)
#pragma unroll
                for (int n = 0; n < 4; ++n)
                    acc[m][n] = __builtin_amdgcn_mfma_f32_16x16x32_f16(
                        af[m], bfr[n], acc[m][n], 0, 0, 0);
        }
    }

#pragma unroll
    for (int m = 0; m < 4; ++m)
#pragma unroll
        for (int n = 0; n < 4; ++n)
#pragma unroll
            for (int r = 0; r < 4; ++r) {
                const int row = bm + wr + m * 16 + g * 4 + r;
                const int col = bn + wc + n * 16 + l15;
                const float v = acc[m][n][r];
                if (F16OUT)
                    ((unsigned short*)Cout)[(size_t)row * N + col] = f2h(v);
                else
                    ((float*)Cout)[(size_t)row * N + col] = v;
            }
}

// ---------------------------------------------------------------------------
// RMSNorm rows of 128, fp16 -> fp16, with post-scale.
// ---------------------------------------------------------------------------
__global__ __launch_bounds__(256)
void rms128_h(const unsigned short* __restrict__ in, unsigned short* __restrict__ out,
              int nrows, float post) {
    const int row  = blockIdx.x * 4 + (threadIdx.x >> 6);
    const int lane = threadIdx.x & 63;
    if (row >= nrows) return;
    const unsigned u = *(const unsigned*)(in + (size_t)row * DH + lane * 2);
    const float a = h2f((unsigned short)(u & 0xffff));
    const float b = h2f((unsigned short)(u >> 16));
    float ss = a * a + b * b;
#pragma unroll
    for (int o = 32; o >= 1; o >>= 1) ss += __shfl_xor(ss, o);
    const float sc = rsqrtf(ss * (1.f / DH) + 1.1920929e-07f) * post;
    const unsigned ov = (unsigned)f2h(a * sc) | ((unsigned)f2h(b * sc) << 16);
    *(unsigned*)(out + (size_t)row * DH + lane * 2) = ov;
}

// ---------------------------------------------------------------------------
// Build Vt[b][hk][d][t] fp16 from Vg[b*T][512] fp16 (32x32 transpose tiles)
// ---------------------------------------------------------------------------
__global__ __launch_bounds__(256)
void vt_build(const unsigned short* __restrict__ Vg, unsigned short* __restrict__ Vt) {
    __shared__ unsigned short Ls[32][36];
    const int t0 = blockIdx.x * 32;
    const int d0 = blockIdx.y * 32;
    const int bh = blockIdx.z;            // b*4 + hk
    const int b = bh >> 2, hk = bh & 3;
    const int i = threadIdx.x;
    {
        const int tr = i >> 3, d4 = (i & 7) * 4;
        const unsigned short* src = Vg + (size_t)(b * TT + t0 + tr) * KVC + hk * DH + d0 + d4;
        const unsigned u0 = *(const unsigned*)(src);
        const unsigned u1 = *(const unsigned*)(src + 2);
        Ls[tr][d4 + 0] = (unsigned short)(u0 & 0xffff);
        Ls[tr][d4 + 1] = (unsigned short)(u0 >> 16);
        Ls[tr][d4 + 2] = (unsigned short)(u1 & 0xffff);
        Ls[tr][d4 + 3] = (unsigned short)(u1 >> 16);
    }
    __syncthreads();
    {
        const int dr = i >> 3, t4 = (i & 7) * 4;
        unsigned short* dst = Vt + ((size_t)bh * DH + d0 + dr) * TT + t0 + t4;
        const unsigned o0 = (unsigned)Ls[t4 + 0][dr] | ((unsigned)Ls[t4 + 1][dr] << 16);
        const unsigned o1 = (unsigned)Ls[t4 + 2][dr] | ((unsigned)Ls[t4 + 3][dr] << 16);
        *(unsigned*)(dst)     = o0;
        *(unsigned*)(dst + 2) = o1;
    }
}

// ---------------------------------------------------------------------------
// Flash attention, fp16 16x16x32 MFMA (R11 = R8 structure + prefetch).
// Block: 256 thr (4 waves), 64 q-rows (16/wave). KVBLK=32, double-buffered
// K/V (36KB LDS -> 4 blocks/CU preserved). Per tile: issue next tile's
// global_load_lds BEFORE compute; vmcnt(0)+barrier at tile end lands free.
// Fused in-register Q-rmsnorm*log2e (shfl_xor 16,32 over the 4 g-lanes).
// Row-sum via ones-column MFMA (acc[8]); defer-max shuffle-free common path.
// ---------------------------------------------------------------------------
__global__ __launch_bounds__(256, 4)
void attn_mfma(const unsigned short* __restrict__ Qb, const unsigned short* __restrict__ Kb,
               const unsigned short* __restrict__ Vt, unsigned short* __restrict__ Yb) {
    __shared__ __align__(16) unsigned short Ks[2][32 * 128];   // [key][d] swizzled
    __shared__ __align__(16) unsigned short Vs[2][128 * 32];   // [d][key] swizzled
    __shared__ __align__(16) unsigned short Ps[4][16 * 32];    // per-wave [q][key]

    const int tid  = threadIdx.x;
    const int lane = tid & 63, wid = tid >> 6;
    const int g = lane >> 4, l15 = lane & 15;
    const int q0 = blockIdx.x * 64;
    const int bh = blockIdx.y;
    const int b = bh >> 4, h = bh & 15, hk = h >> 2;

    const size_t kbase = (size_t)(b * TT) * KVC + hk * DH;
    const size_t vbase = (size_t)(b * HKV_ + hk) * DH * TT;

    // stage one 32-key K/V tile into buffer `buf` (4 gll16 per thread)
#define STAGE(buf, st)                                                         \
    do {                                                                       \
        _Pragma("unroll")                                                      \
        for (int r = 0; r < 2; ++r) {                                          \
            const int qq = r * 256 + tid;                                      \
            const int key = qq >> 4, c = qq & 15, sc = c ^ (key & 7);          \
            gll16(Kb + kbase + (size_t)((st) + key) * KVC + sc * 8,            \
                  &Ks[buf][qq * 8]);                                           \
        }                                                                      \
        _Pragma("unroll")                                                      \
        for (int r = 0; r < 2; ++r) {                                          \
            const int qq = r * 256 + tid;                                      \
            const int d = qq >> 2, c = qq & 3, sc = c ^ (d & 3);               \
            gll16(Vt + vbase + (size_t)d * TT + (st) + sc * 8,                 \
                  &Vs[buf][qq * 8]);                                           \
        }                                                                      \
    } while (0)

    STAGE(0, 0);   // prologue: tile 0 in flight while we load/norm Q

    // ---- Q fragments (16 q-rows/wave; lane: row l15, dims g*8+kk*32+j) ----
    f16x8 qf[4];
    {
        const unsigned short* qp =
            Qb + (size_t)(b * TT + q0 + wid * 16 + l15) * CC + h * DH + g * 8;
#pragma unroll
        for (int kk = 0; kk < 4; ++kk) qf[kk] = *(const f16x8*)(qp + kk * 32);
    }
    // fused rmsnorm * log2e: row sum-of-squares over the 4 lanes sharing l15
    {
        float ss = 0.f;
#pragma unroll
        for (int kk = 0; kk < 4; ++kk)
#pragma unroll
            for (int j = 0; j < 8; ++j) { const float v = (float)qf[kk][j]; ss += v * v; }
        ss += __shfl_xor(ss, 16);
        ss += __shfl_xor(ss, 32);
        const float qsc = rsqrtf(ss * (1.f / DH) + 1.1920929e-07f) * 1.4426950408889634f;
#pragma unroll
        for (int kk = 0; kk < 4; ++kk)
#pragma unroll
            for (int j = 0; j < 8; ++j)
                qf[kk][j] = (_Float16)((float)qf[kk][j] * qsc);
    }

    // ones B-frag: column 0 of the 9th output block accumulates row-sum l
    f16x8 ones_b;
    {
        const _Float16 v = (l15 == 0) ? (_Float16)1.0f : (_Float16)0.0f;
#pragma unroll
        for (int j = 0; j < 8; ++j) ones_b[j] = v;
    }

    float mr[4];
    f32x4 acc[9] = {};
#pragma unroll
    for (int r = 0; r < 4; ++r) mr[r] = -3.0e38f;

    unsigned short* pw = Ps[wid];

    asm volatile("s_waitcnt vmcnt(0)" ::: "memory");
    __builtin_amdgcn_s_barrier();

    const int NT = TT / 32;   // 64 tiles
    for (int t = 0; t < NT; ++t) {
        const int cur = t & 1;
        if (t + 1 < NT) STAGE(cur ^ 1, (t + 1) * 32);   // prefetch next tile

        const unsigned short* ksp = Ks[cur];
        const unsigned short* vsp = Vs[cur];

        // ---- S = Q K^T (32 keys: 2 col-frags x 4 dh-steps) ----
        f32x4 s[2] = {};
        __builtin_amdgcn_s_setprio(1);
#pragma unroll
        for (int kk = 0; kk < 4; ++kk)
#pragma unroll
            for (int n = 0; n < 2; ++n) {
                const int key = n * 16 + l15;
                const int ch = (kk * 4 + g) ^ (key & 7);
                const f16x8 kf = *(const f16x8*)&ksp[key * 128 + ch * 8];
                s[n] = __builtin_amdgcn_mfma_f32_16x16x32_f16(qf[kk], kf, s[n], 0, 0, 0);
            }
        __builtin_amdgcn_s_setprio(0);

        // ---- defer-max: shuffle-free common path ----
        float m0[4];
        bool need = false;
#pragma unroll
        for (int r = 0; r < 4; ++r) {
            m0[r] = fmaxf(s[0][r], s[1][r]);
            need = need || (m0[r] > mr[r] + 8.f);
        }
        if (__any(need)) {
            float scale[4];
#pragma unroll
            for (int r = 0; r < 4; ++r) {
                float mx = m0[r];
#pragma unroll
                for (int o = 8; o >= 1; o >>= 1) mx = fmaxf(mx, __shfl_xor(mx, o));
                const float mn = fmaxf(mr[r], mx);
                scale[r] = __builtin_amdgcn_exp2f(mr[r] - mn);
                mr[r] = mn;
            }
#pragma unroll
            for (int f = 0; f < 9; ++f) {
                acc[f][0] *= scale[0]; acc[f][1] *= scale[1];
                acc[f][2] *= scale[2]; acc[f][3] *= scale[3];
            }
        }

        // ---- P = exp2(S - m) -> per-wave LDS (4-chunk swizzle) ----
#pragma unroll
        for (int n = 0; n < 2; ++n) {
            const int colc = n * 2 + (l15 >> 3);
            const int cel  = l15 & 7;
#pragma unroll
            for (int r = 0; r < 4; ++r) {
                const float p = __builtin_amdgcn_exp2f(s[n][r] - mr[r]);
                const int row = g * 4 + r;
                const int ch = colc ^ (row & 3);
                pw[row * 32 + ch * 8 + cel] = f2h(p);
            }
        }

        // ---- O += P V ; l += P 1 (single K=32 step) ----
        __builtin_amdgcn_s_setprio(1);
        {
            const int ch = g ^ (l15 & 3);
            const f16x8 pa = *(const f16x8*)&pw[l15 * 32 + ch * 8];
#pragma unroll
            for (int f = 0; f < 8; ++f) {
                const int dr = f * 16 + l15;
                const int vch = g ^ (dr & 3);
                const f16x8 vf = *(const f16x8*)&vsp[dr * 32 + vch * 8];
                acc[f] = __builtin_amdgcn_mfma_f32_16x16x32_f16(pa, vf, acc[f], 0, 0, 0);
            }
            acc[8] = __builtin_amdgcn_mfma_f32_16x16x32_f16(pa, ones_b, acc[8], 0, 0, 0);
        }
        __builtin_amdgcn_s_setprio(0);

        // prefetched loads have had the whole compute phase to land
        asm volatile("s_waitcnt vmcnt(0)" ::: "memory");
        __builtin_amdgcn_s_barrier();
    }
#undef STAGE

    // ---- finalize: l at col0 of acc[8] (lane l15==0 of each group) ----
    float inv[4];
#pragma unroll
    for (int r = 0; r < 4; ++r) {
        const float l = __shfl(acc[8][r], lane & 48);
        inv[r] = 1.f / l;
    }
#pragma unroll
    for (int f = 0; f < 8; ++f)
#pragma unroll
        for (int r = 0; r < 4; ++r) {
            const int t = q0 + wid * 16 + g * 4 + r;
            const int col = h * DH + f * 16 + l15;
            Yb[(size_t)(b * TT + t) * CC + col] = f2h(acc[f][r] * inv[r]);
        }
}

// ---------------------------------------------------------------------------
// RMSNorm rows of 2048, fp32 in-place (final output norm)
// ---------------------------------------------------------------------------
__global__ __launch_bounds__(256)
void rms2048_inplace(float* __restrict__ d) {
    __shared__ float red[4];
    const int tid = threadIdx.x;
    float* p = d + (size_t)blockIdx.x * CC;
    float4 a = *(float4*)&p[tid * 8];
    float4 b = *(float4*)&p[tid * 8 + 4];
    float ss = a.x * a.x + a.y * a.y + a.z * a.z + a.w * a.w +
               b.x * b.x + b.y * b.y + b.z * b.z + b.w * b.w;
#pragma unroll
    for (int o = 32; o >= 1; o >>= 1) ss += __shfl_xor(ss, o);
    if ((tid & 63) == 0) red[tid >> 6] = ss;
    __syncthreads();
    const float tot = red[0] + red[1] + red[2] + red[3];
    const float sc = rsqrtf(tot * (1.f / CC) + 1.1920929e-07f);
    a.x *= sc; a.y *= sc; a.z *= sc; a.w *= sc;
    b.x *= sc; b.y *= sc; b.z *= sc; b.w *= sc;
    *(float4*)&p[tid * 8]     = a;
    *(float4*)&p[tid * 8 + 4] = b;
}

// ---------------------------------------------------------------------------
extern "C" void kernel_launch(void* const* d_in, const int* in_sizes, int n_in,
                              void* d_out, int out_size, void* d_ws, size_t ws_size,
                              hipStream_t stream) {
    const float* x  = (const float*)d_in[0];
    const float* Wq = (const float*)d_in[1];
    // d_in[2] = Wk — unused by the reference (K = rmsnorm(V))
    const float* Wv = (const float*)d_in[3];
    const float* Wo = (const float*)d_in[4];
    float* out = (float*)d_out;

    char* ws = (char*)d_ws;
    const size_t MB = 1024 * 1024;
    unsigned short* xb  = (unsigned short*)(ws);             // 16 MB
    unsigned short* WqT = (unsigned short*)(ws + 16 * MB);   //  8 MB
    unsigned short* WoT = WqT;                               // reuse after gemm Q
    unsigned short* WvT = (unsigned short*)(ws + 24 * MB);   //  2 MB
    unsigned short* Qg  = (unsigned short*)(ws + 26 * MB);   // 16 MB (raw Q, normed in attn)
    unsigned short* Vg  = (unsigned short*)(ws + 42 * MB);   //  4 MB
    unsigned short* Kb  = (unsigned short*)(ws + 46 * MB);   //  4 MB
    unsigned short* Vt  = (unsigned short*)(ws + 50 * MB);   //  4 MB
    unsigned short* Yb  = (unsigned short*)(ws + 54 * MB);   // 16 MB  (peak 70 MB)

    const dim3 blk(256);

    cast_f16<<<2048, blk, 0, stream>>>(x, xb, MM * CC / 8);
    tcast<<<dim3(CC / 32, CC / 32), blk, 0, stream>>>(Wq, WqT, CC, CC);
    tcast<<<dim3(KVC / 32, CC / 32), blk, 0, stream>>>(Wv, WvT, CC, KVC);

    gemm_bt<1><<<dim3(CC / 128, MM / 128), blk, 0, stream>>>(xb, WqT, Qg, MM, CC, CC);
    gemm_bt<1><<<dim3(KVC / 128, MM / 128), blk, 0, stream>>>(xb, WvT, Vg, MM, KVC, CC);

    tcast<<<dim3(CC / 32, CC / 32), blk, 0, stream>>>(Wo, WoT, CC, CC);  // after gemm Q

    rms128_h<<<MM * HKV_ / 4, blk, 0, stream>>>(Vg, Kb, MM * HKV_, 1.f); // K = norm(V)
    vt_build<<<dim3(TT / 32, DH / 32, BB * HKV_), blk, 0, stream>>>(Vg, Vt);

    attn_mfma<<<dim3(TT / 64, BB * HQ_), blk, 0, stream>>>(Qg, Kb, Vt, Yb);

    gemm_bt<0><<<dim3(CC / 128, MM / 128), blk, 0, stream>>>(Yb, WoT, out, MM, CC, CC);
    rms2048_inplace<<<MM, blk, 0, stream>>>(out);
}